// Round 1
// baseline (232.914 us; speedup 1.0000x reference)
//
#include <hip/hip_runtime.h>
#include <hip/hip_bf16.h>

#define T_STEPS 100
#define D_IN    65536
#define HID     256
#define HTOT    512      // actor 256 + critic 256 combined
#define BETA    0.95f
#define THRESH  1.0f

// -------- GEMM1 split-K partials: P[s][t][h] = sum_{k in split s} x[t][k]*W1[h][k]
// grid: (8 h-tiles of 64, NS k-splits), block 512
__global__ __launch_bounds__(512) void k_gemm1(
    const float* __restrict__ x,     // [100][65536]
    const float* __restrict__ aW1,   // [256][65536]
    const float* __restrict__ cW1,   // [256][65536]
    float* __restrict__ P,           // [NS][100][512]
    int Kc)
{
    const int ht  = blockIdx.x;      // 0..7  (0..3 actor, 4..7 critic)
    const int s   = blockIdx.y;
    const int tid = threadIdx.x;

    const float* Wbase = (ht < 4) ? (aW1 + (size_t)ht * 64 * D_IN)
                                  : (cW1 + (size_t)(ht - 4) * 64 * D_IN);

    // LDS: transposed tiles, strides are multiples of 16B for b128 reads
    __shared__ float xs [32][132];   // [k][t]  stride 528B = 33*16
    __shared__ float wsm[32][68];    // [k][h]  stride 272B = 17*16

    float acc[4][4];
#pragma unroll
    for (int i = 0; i < 4; i++)
#pragma unroll
        for (int j = 0; j < 4; j++) acc[i][j] = 0.f;

    const int tg = tid >> 4;         // 0..31 -> t block of 4
    const int hg = tid & 15;         // 0..15 -> h block of 4
    const int kp = tid & 7;          // staging: k part (4 floats each)
    const int th = tid >> 3;         // staging: row 0..63

    const int k0 = s * Kc;
    for (int kb = k0; kb < k0 + Kc; kb += 32) {
        // stage x: 128 t rows (pad t>=100 with zeros) x 32 k, transposed
#pragma unroll
        for (int tt = 0; tt < 2; tt++) {
            int t = tt * 64 + th;
            float4 v = make_float4(0.f, 0.f, 0.f, 0.f);
            if (t < T_STEPS) v = *(const float4*)(x + (size_t)t * D_IN + kb + kp * 4);
            xs[kp * 4 + 0][t] = v.x; xs[kp * 4 + 1][t] = v.y;
            xs[kp * 4 + 2][t] = v.z; xs[kp * 4 + 3][t] = v.w;
        }
        // stage w: 64 h rows x 32 k, transposed
        {
            float4 v = *(const float4*)(Wbase + (size_t)th * D_IN + kb + kp * 4);
            wsm[kp * 4 + 0][th] = v.x; wsm[kp * 4 + 1][th] = v.y;
            wsm[kp * 4 + 2][th] = v.z; wsm[kp * 4 + 3][th] = v.w;
        }
        __syncthreads();

#pragma unroll
        for (int k = 0; k < 32; k++) {
            float4 xv = *(const float4*)&xs [k][tg * 4];
            float4 wv = *(const float4*)&wsm[k][hg * 4];
            acc[0][0] += xv.x * wv.x; acc[0][1] += xv.x * wv.y;
            acc[0][2] += xv.x * wv.z; acc[0][3] += xv.x * wv.w;
            acc[1][0] += xv.y * wv.x; acc[1][1] += xv.y * wv.y;
            acc[1][2] += xv.y * wv.z; acc[1][3] += xv.y * wv.w;
            acc[2][0] += xv.z * wv.x; acc[2][1] += xv.z * wv.y;
            acc[2][2] += xv.z * wv.z; acc[2][3] += xv.z * wv.w;
            acc[3][0] += xv.w * wv.x; acc[3][1] += xv.w * wv.y;
            acc[3][2] += xv.w * wv.z; acc[3][3] += xv.w * wv.w;
        }
        __syncthreads();
    }

    // store partials (deterministic: each block owns its [s][.,h-range] slice)
#pragma unroll
    for (int tt = 0; tt < 4; tt++) {
        int t = tg * 4 + tt;
        if (t < T_STEPS) {
            float4 v = make_float4(acc[tt][0], acc[tt][1], acc[tt][2], acc[tt][3]);
            *(float4*)(P + (size_t)s * T_STEPS * HTOT + (size_t)t * HTOT
                         + ht * 64 + hg * 4) = v;
        }
    }
}

// -------- reduce partials + bias -> cur1[t][h]
__global__ __launch_bounds__(256) void k_reduce(
    const float* __restrict__ P,
    const float* __restrict__ ab1, const float* __restrict__ cb1,
    float* __restrict__ cur1, int NS)
{
    int g = blockIdx.x * 256 + threadIdx.x;   // 0..51199
    int h = g & (HTOT - 1);
    float sum = (h < HID) ? ab1[h] : cb1[h - HID];
    for (int ss = 0; ss < NS; ss++)
        sum += P[(size_t)ss * T_STEPS * HTOT + g];
    cur1[g] = sum;
}

// -------- LIF1 (per-neuron) + GEMM2 (bitmask) + LIF2 + softmax, single block
__global__ __launch_bounds__(512) void k_tail(
    const float* __restrict__ cur1,   // [100][512]
    const float* __restrict__ aW2,    // [20][256]
    const float* __restrict__ ab2,    // [20]
    const float* __restrict__ cW2,    // [1][256]
    const float* __restrict__ cb2,    // [1]
    float* __restrict__ out)          // [3] policy0, policy1, critic_mem
{
    __shared__ float W2L[21][256];
    __shared__ unsigned long long bits[T_STEPS][8];
    __shared__ float cur2L[T_STEPS][22];
    __shared__ float red[32];
    const int tid = threadIdx.x;

    for (int idx = tid; idx < 21 * 256; idx += 512) {
        int j = idx >> 8, i = idx & 255;
        W2L[j][i] = (j < 20) ? aW2[j * 256 + i] : cW2[i];
    }

    // LIF1: thread = hidden neuron (0..255 actor, 256..511 critic)
    {
        float mem = 0.f;
        const int w = tid >> 6;
        for (int t = 0; t < T_STEPS; t++) {
            float c = cur1[t * HTOT + tid];
            float reset = (mem > THRESH) ? THRESH : 0.f;
            mem = BETA * mem + c - reset;
            unsigned long long m = __ballot(mem > THRESH);
            if ((tid & 63) == 0) bits[t][w] = m;
        }
    }
    __syncthreads();

    // GEMM2: cur2[t][j], j: 0..19 actor, 20 critic.  2100 tasks.
    for (int p = tid; p < T_STEPS * 21; p += 512) {
        int t = p / 21, j = p - t * 21;
        float acc = (j < 20) ? ab2[j] : cb2[0];
        int wbase = (j < 20) ? 0 : 4;
#pragma unroll
        for (int w = 0; w < 4; w++) {
            unsigned long long m = bits[t][wbase + w];
#pragma unroll
            for (int b = 0; b < 64; b++) {
                acc += ((m >> b) & 1ULL) ? W2L[j][w * 64 + b] : 0.f;
            }
        }
        cur2L[t][j] = acc;
    }
    __syncthreads();

    // LIF2
    if (tid < 21) {
        float mem = 0.f, spksum = 0.f;
        for (int t = 0; t < T_STEPS; t++) {
            float reset = (mem > THRESH) ? THRESH : 0.f;
            mem = BETA * mem + cur2L[t][tid] - reset;
            if (tid < 20) spksum += (mem > THRESH) ? 1.f : 0.f;
        }
        red[tid] = spksum;
        if (tid == 20) out[2] = mem;   // critic final membrane
    }
    __syncthreads();

    if (tid == 0) {
        float a0 = 0.f, a1 = 0.f;
        for (int j = 0;  j < 10; j++) a0 += red[j];
        for (int j = 10; j < 20; j++) a1 += red[j];
        float mx = fmaxf(a0, a1);
        float e0 = expf(a0 - mx), e1 = expf(a1 - mx);
        float inv = 1.f / (e0 + e1);
        out[0] = e0 * inv;
        out[1] = e1 * inv;
    }
}

extern "C" void kernel_launch(void* const* d_in, const int* in_sizes, int n_in,
                              void* d_out, int out_size, void* d_ws, size_t ws_size,
                              hipStream_t stream) {
    const float* x   = (const float*)d_in[0];
    const float* aW1 = (const float*)d_in[1];
    const float* ab1 = (const float*)d_in[2];
    const float* aW2 = (const float*)d_in[3];
    const float* ab2 = (const float*)d_in[4];
    const float* cW1 = (const float*)d_in[5];
    const float* cb1 = (const float*)d_in[6];
    const float* cW2 = (const float*)d_in[7];
    const float* cb2 = (const float*)d_in[8];
    float* out = (float*)d_out;

    // split-K factor, shrink if workspace is small (deterministic given ws_size)
    int NS = 64;
    while (NS > 4 &&
           ((size_t)NS * T_STEPS * HTOT + T_STEPS * HTOT) * sizeof(float) > ws_size)
        NS >>= 1;
    int Kc = D_IN / NS;

    float* P    = (float*)d_ws;                              // [NS][100][512]
    float* cur1 = (float*)d_ws + (size_t)NS * T_STEPS * HTOT; // [100][512]

    k_gemm1<<<dim3(8, NS), 512, 0, stream>>>(x, aW1, cW1, P, Kc);
    k_reduce<<<(T_STEPS * HTOT) / 256, 256, 0, stream>>>(P, ab1, cb1, cur1, NS);
    k_tail<<<1, 512, 0, stream>>>(cur1, aW2, ab2, cW2, cb2, out);
}

// Round 2
// 152.864 us; speedup vs baseline: 1.5237x; 1.5237x over previous
//
#include <hip/hip_runtime.h>
#include <hip/hip_bf16.h>

#define T_STEPS 100
#define D_IN    65536
#define HID     256
#define HTOT    512
#define BETA    0.95f
#define THRESH  1.0f

#define BM 128
#define BN 128
#define BK 64

typedef __bf16 bf16x8 __attribute__((ext_vector_type(8)));
typedef __bf16 bf16x4 __attribute__((ext_vector_type(4)));
typedef float  f32x16 __attribute__((ext_vector_type(16)));

// GEMM1 via bf16 hi/mid split, 3-product MFMA. C[t][h] partials per k-split.
// grid: (4 h-tiles of 128, NS k-splits), block 256 (4 waves of 64x64)
__global__ __launch_bounds__(256) void k_gemm1(
    const float* __restrict__ x,     // [100][65536]
    const float* __restrict__ aW1,   // [256][65536]
    const float* __restrict__ cW1,   // [256][65536]
    float* __restrict__ P,           // [NS][100][512]
    int Kc)
{
    const int ht  = blockIdx.x;      // 0..3
    const int s   = blockIdx.y;      // k-split
    const int tid = threadIdx.x;

    __shared__ __bf16 Ah[BM][BK], Am[BM][BK], Bh[BN][BK], Bm[BN][BK];

    const float* Wb = (ht < 2) ? (aW1 + (size_t)ht * 128 * D_IN)
                               : (cW1 + (size_t)(ht - 2) * 128 * D_IN);

    const int lane = tid & 63;
    const int wv   = tid >> 6;           // 0..3
    const int wt   = (wv & 1) * 64;      // wave t-offset
    const int wh   = (wv >> 1) * 64;     // wave h-offset

    const int srow = tid >> 2;           // staging row 0..63 (and +64)
    const int kq   = tid & 3;            // k-quarter (16 floats)

    f32x16 acc[2][2];
    for (int p = 0; p < 2; p++)
        for (int q = 0; q < 2; q++)
            for (int i = 0; i < 16; i++) acc[p][q][i] = 0.f;

    const int k0 = s * Kc;
    for (int kb = k0; kb < k0 + Kc; kb += BK) {
        // ---- global -> regs (fp32)
        float4 av[2][4], bv[2][4];
#pragma unroll
        for (int rr = 0; rr < 2; rr++) {
            const int r = srow + rr * 64;
#pragma unroll
            for (int j = 0; j < 4; j++) {
                av[rr][j] = (r < T_STEPS)
                    ? *(const float4*)(x + (size_t)r * D_IN + kb + kq * 16 + j * 4)
                    : make_float4(0.f, 0.f, 0.f, 0.f);
                bv[rr][j] = *(const float4*)(Wb + (size_t)r * D_IN + kb + kq * 16 + j * 4);
            }
        }
        __syncthreads();   // previous chunk's compute done reading LDS
        // ---- convert + swizzled LDS write
#pragma unroll
        for (int rr = 0; rr < 2; rr++) {
            const int r = srow + rr * 64;
#pragma unroll
            for (int j = 0; j < 4; j++) {
                const int ke   = kq * 16 + j * 4;
                const int slot = ke >> 3, within = ke & 7;
                const int pe   = ((slot ^ (r & 7)) << 3) + within;
                float af[4] = {av[rr][j].x, av[rr][j].y, av[rr][j].z, av[rr][j].w};
                float bf[4] = {bv[rr][j].x, bv[rr][j].y, bv[rr][j].z, bv[rr][j].w};
                bf16x4 ah_, am_, bh_, bm_;
#pragma unroll
                for (int e = 0; e < 4; e++) {
                    __bf16 h = (__bf16)af[e];
                    ah_[e] = h; am_[e] = (__bf16)(af[e] - (float)h);
                    __bf16 g = (__bf16)bf[e];
                    bh_[e] = g; bm_[e] = (__bf16)(bf[e] - (float)g);
                }
                *(bf16x4*)&Ah[r][pe] = ah_;
                *(bf16x4*)&Am[r][pe] = am_;
                *(bf16x4*)&Bh[r][pe] = bh_;
                *(bf16x4*)&Bm[r][pe] = bm_;
            }
        }
        __syncthreads();
        // ---- 4 k16-steps of MFMA
#pragma unroll
        for (int s16 = 0; s16 < 4; s16++) {
            bf16x8 a_h[2], a_m[2], b_h[2], b_m[2];
            const int slot = s16 * 2 + (lane >> 5);
#pragma unroll
            for (int p = 0; p < 2; p++) {
                const int r  = wt + p * 32 + (lane & 31);
                const int pe = (slot ^ (r & 7)) << 3;
                a_h[p] = *(const bf16x8*)&Ah[r][pe];
                a_m[p] = *(const bf16x8*)&Am[r][pe];
            }
#pragma unroll
            for (int q = 0; q < 2; q++) {
                const int r  = wh + q * 32 + (lane & 31);
                const int pe = (slot ^ (r & 7)) << 3;
                b_h[q] = *(const bf16x8*)&Bh[r][pe];
                b_m[q] = *(const bf16x8*)&Bm[r][pe];
            }
#pragma unroll
            for (int p = 0; p < 2; p++)
#pragma unroll
                for (int q = 0; q < 2; q++) {
                    acc[p][q] = __builtin_amdgcn_mfma_f32_32x32x16_bf16(a_m[p], b_h[q], acc[p][q], 0, 0, 0);
                    acc[p][q] = __builtin_amdgcn_mfma_f32_32x32x16_bf16(a_h[p], b_m[q], acc[p][q], 0, 0, 0);
                    acc[p][q] = __builtin_amdgcn_mfma_f32_32x32x16_bf16(a_h[p], b_h[q], acc[p][q], 0, 0, 0);
                }
        }
    }

    // ---- store partials
    const int col   = lane & 31;
    const int rbase = 4 * (lane >> 5);
#pragma unroll
    for (int p = 0; p < 2; p++)
#pragma unroll
        for (int q = 0; q < 2; q++)
#pragma unroll
            for (int reg = 0; reg < 16; reg++) {
                const int row = (reg & 3) + rbase + 8 * (reg >> 2);
                const int t   = wt + p * 32 + row;
                if (t < T_STEPS) {
                    const int h = ht * BN + wh + q * 32 + col;
                    P[(size_t)s * T_STEPS * HTOT + (size_t)t * HTOT + h] = acc[p][q][reg];
                }
            }
}

// reduce partials + bias -> cur1[t][h]
__global__ __launch_bounds__(256) void k_reduce(
    const float* __restrict__ P,
    const float* __restrict__ ab1, const float* __restrict__ cb1,
    float* __restrict__ cur1, int NS)
{
    int g = blockIdx.x * 256 + threadIdx.x;   // 0..51199
    int h = g & (HTOT - 1);
    float sum = (h < HID) ? ab1[h] : cb1[h - HID];
    for (int ss = 0; ss < NS; ss++)
        sum += P[(size_t)ss * T_STEPS * HTOT + g];
    cur1[g] = sum;
}

// LIF1 + GEMM2 (bitmask, wave-per-j) + LIF2 + softmax, single block
__global__ __launch_bounds__(512) void k_tail(
    const float* __restrict__ cur1,   // [100][512]
    const float* __restrict__ aW2,    // [20][256]
    const float* __restrict__ ab2,    // [20]
    const float* __restrict__ cW2,    // [1][256]
    const float* __restrict__ cb2,    // [1]
    float* __restrict__ out)          // [3]
{
    __shared__ float W2L[21][256];
    __shared__ unsigned long long bits[T_STEPS][9];   // padded stride
    __shared__ float cur2L[T_STEPS][22];
    __shared__ float red[32];
    const int tid = threadIdx.x;

    for (int idx = tid; idx < 21 * 256; idx += 512) {
        int j = idx >> 8, i = idx & 255;
        W2L[j][i] = (j < 20) ? aW2[j * 256 + i] : cW2[i];
    }

    // LIF1: thread = hidden neuron
    {
        float mem = 0.f;
        const int w = tid >> 6;
        for (int t = 0; t < T_STEPS; t++) {
            float c = cur1[t * HTOT + tid];
            float reset = (mem > THRESH) ? THRESH : 0.f;
            mem = BETA * mem + c - reset;
            unsigned long long m = __ballot(mem > THRESH);
            if ((tid & 63) == 0) bits[t][w] = m;
        }
    }
    __syncthreads();

    // GEMM2: wave wv owns j = wv, wv+8, wv+16; lanes cover t. W2L reads are
    // wave-uniform -> LDS broadcast (round-1 version was a 64-way conflict).
    {
        const int ln = tid & 63, wv = tid >> 6;
        for (int j = wv; j < 21; j += 8) {
            const float bias  = (j < 20) ? ab2[j] : cb2[0];
            const int   wbase = (j < 20) ? 0 : 4;
            const float* Wj = &W2L[j][0];
            for (int th = 0; th < 2; th++) {
                int t = th * 64 + ln;
                if (t < T_STEPS) {
                    float acc = bias;
#pragma unroll
                    for (int w = 0; w < 4; w++) {
                        unsigned long long m = bits[t][wbase + w];
                        unsigned lo = (unsigned)m, hi = (unsigned)(m >> 32);
#pragma unroll
                        for (int b = 0; b < 32; b++)
                            acc += ((lo >> b) & 1) ? Wj[w * 64 + b] : 0.f;
#pragma unroll
                        for (int b = 0; b < 32; b++)
                            acc += ((hi >> b) & 1) ? Wj[w * 64 + 32 + b] : 0.f;
                    }
                    cur2L[t][j] = acc;
                }
            }
        }
    }
    __syncthreads();

    // LIF2
    if (tid < 21) {
        float mem = 0.f, spksum = 0.f;
        for (int t = 0; t < T_STEPS; t++) {
            float reset = (mem > THRESH) ? THRESH : 0.f;
            mem = BETA * mem + cur2L[t][tid] - reset;
            if (tid < 20) spksum += (mem > THRESH) ? 1.f : 0.f;
        }
        red[tid] = spksum;
        if (tid == 20) out[2] = mem;
    }
    __syncthreads();

    if (tid == 0) {
        float a0 = 0.f, a1 = 0.f;
        for (int j = 0;  j < 10; j++) a0 += red[j];
        for (int j = 10; j < 20; j++) a1 += red[j];
        float mx = fmaxf(a0, a1);
        float e0 = expf(a0 - mx), e1 = expf(a1 - mx);
        float inv = 1.f / (e0 + e1);
        out[0] = e0 * inv;
        out[1] = e1 * inv;
    }
}

extern "C" void kernel_launch(void* const* d_in, const int* in_sizes, int n_in,
                              void* d_out, int out_size, void* d_ws, size_t ws_size,
                              hipStream_t stream) {
    const float* x   = (const float*)d_in[0];
    const float* aW1 = (const float*)d_in[1];
    const float* ab1 = (const float*)d_in[2];
    const float* aW2 = (const float*)d_in[3];
    const float* ab2 = (const float*)d_in[4];
    const float* cW1 = (const float*)d_in[5];
    const float* cb1 = (const float*)d_in[6];
    const float* cW2 = (const float*)d_in[7];
    const float* cb2 = (const float*)d_in[8];
    float* out = (float*)d_out;

    int NS = 128;
    while (NS > 8 &&
           ((size_t)(NS + 1) * T_STEPS * HTOT) * sizeof(float) > ws_size)
        NS >>= 1;
    int Kc = D_IN / NS;   // multiple of BK for all NS in {8..128}

    float* P    = (float*)d_ws;                                // [NS][100][512]
    float* cur1 = (float*)d_ws + (size_t)NS * T_STEPS * HTOT;  // [100][512]

    k_gemm1<<<dim3(4, NS), 256, 0, stream>>>(x, aW1, cW1, P, Kc);
    k_reduce<<<(T_STEPS * HTOT) / 256, 256, 0, stream>>>(P, ab1, cb1, cur1, NS);
    k_tail<<<1, 512, 0, stream>>>(cur1, aW2, ab2, cW2, cb2, out);
}

// Round 3
// 111.017 us; speedup vs baseline: 2.0980x; 1.3769x over previous
//
#include <hip/hip_runtime.h>
#include <hip/hip_bf16.h>

#define T_STEPS 100
#define D_IN    65536
#define HID     256
#define HTOT    512
#define BETA    0.95f
#define THRESH  1.0f

#define BM 128
#define BN 128
#define BK 64

typedef __bf16 bf16x8 __attribute__((ext_vector_type(8)));
typedef __bf16 bf16x4 __attribute__((ext_vector_type(4)));
typedef float  f32x16 __attribute__((ext_vector_type(16)));

// GEMM1, bf16 hi/mid 3-product MFMA, register-double-buffered prefetch.
// grid: (4 h-tiles of 128, NS k-splits), block 512 = 8 waves (2t x 4h of 64x32)
__global__ __launch_bounds__(512) void k_gemm1(
    const float* __restrict__ x,     // [100][65536]
    const float* __restrict__ aW1,   // [256][65536]
    const float* __restrict__ cW1,   // [256][65536]
    float* __restrict__ P,           // [NS][100][512]
    int Kc)
{
    const int ht  = blockIdx.x;      // 0..3
    const int s   = blockIdx.y;      // k-split
    const int tid = threadIdx.x;

    __shared__ __bf16 Ah[BM][BK], Am[BM][BK], Bh[BN][BK], Bm[BN][BK];

    const float* Wb = (ht < 2) ? (aW1 + (size_t)ht * 128 * D_IN)
                               : (cW1 + (size_t)(ht - 2) * 128 * D_IN);

    const int lane = tid & 63;
    const int wv   = tid >> 6;           // 0..7
    const int wt   = (wv & 1) * 64;      // wave t-offset
    const int wh   = (wv >> 1) * 32;     // wave h-offset

    const int srow = tid >> 2;           // staging row 0..127
    const int kq   = tid & 3;            // k-quarter (16 floats)

    const float* xrow = x  + (size_t)srow * D_IN + kq * 16;
    const float* wrow = Wb + (size_t)srow * D_IN + kq * 16;
    const bool   xok  = (srow < T_STEPS);

    f32x16 acc0, acc1;
#pragma unroll
    for (int i = 0; i < 16; i++) { acc0[i] = 0.f; acc1[i] = 0.f; }

    float4 avA[4], bvA[4], avB[4], bvB[4];

    const int k0     = s * Kc;
    const int niters = Kc / BK;          // even (>=8)

#define LOADSET(av, bv, it) do {                                              \
    const int kb_ = k0 + (it) * BK;                                           \
    _Pragma("unroll")                                                         \
    for (int j = 0; j < 4; j++) {                                             \
        if (xok) av[j] = *(const float4*)(xrow + kb_ + j * 4);                \
        else     av[j] = make_float4(0.f, 0.f, 0.f, 0.f);                     \
        bv[j] = *(const float4*)(wrow + kb_ + j * 4);                         \
    } } while (0)

#define CONVWRITE(av, bv) do {                                                \
    _Pragma("unroll")                                                         \
    for (int j = 0; j < 4; j++) {                                             \
        const int ke   = kq * 16 + j * 4;                                     \
        const int slot = ke >> 3, within = ke & 7;                            \
        const int pe   = ((slot ^ (srow & 7)) << 3) + within;                 \
        float af[4]  = {av[j].x, av[j].y, av[j].z, av[j].w};                  \
        float bf_[4] = {bv[j].x, bv[j].y, bv[j].z, bv[j].w};                  \
        bf16x4 ah_, am_, bh_, bm_;                                            \
        _Pragma("unroll")                                                     \
        for (int e = 0; e < 4; e++) {                                         \
            __bf16 h = (__bf16)af[e];                                         \
            ah_[e] = h; am_[e] = (__bf16)(af[e] - (float)h);                  \
            __bf16 g = (__bf16)bf_[e];                                        \
            bh_[e] = g; bm_[e] = (__bf16)(bf_[e] - (float)g);                 \
        }                                                                     \
        *(bf16x4*)&Ah[srow][pe] = ah_;                                        \
        *(bf16x4*)&Am[srow][pe] = am_;                                        \
        *(bf16x4*)&Bh[srow][pe] = bh_;                                        \
        *(bf16x4*)&Bm[srow][pe] = bm_;                                        \
    } } while (0)

#define MFMAPHASE() do {                                                      \
    _Pragma("unroll")                                                         \
    for (int s16 = 0; s16 < 4; s16++) {                                       \
        const int slot = s16 * 2 + (lane >> 5);                               \
        const int ra0 = wt + (lane & 31), ra1 = ra0 + 32;                     \
        const int rb  = wh + (lane & 31);                                     \
        const int pa0 = (slot ^ (ra0 & 7)) << 3;                              \
        const int pa1 = (slot ^ (ra1 & 7)) << 3;                              \
        const int pb  = (slot ^ (rb  & 7)) << 3;                              \
        bf16x8 a0h = *(const bf16x8*)&Ah[ra0][pa0];                           \
        bf16x8 a0m = *(const bf16x8*)&Am[ra0][pa0];                           \
        bf16x8 a1h = *(const bf16x8*)&Ah[ra1][pa1];                           \
        bf16x8 a1m = *(const bf16x8*)&Am[ra1][pa1];                           \
        bf16x8 b0h = *(const bf16x8*)&Bh[rb][pb];                             \
        bf16x8 b0m = *(const bf16x8*)&Bm[rb][pb];                             \
        acc0 = __builtin_amdgcn_mfma_f32_32x32x16_bf16(a0m, b0h, acc0, 0,0,0);\
        acc0 = __builtin_amdgcn_mfma_f32_32x32x16_bf16(a0h, b0m, acc0, 0,0,0);\
        acc0 = __builtin_amdgcn_mfma_f32_32x32x16_bf16(a0h, b0h, acc0, 0,0,0);\
        acc1 = __builtin_amdgcn_mfma_f32_32x32x16_bf16(a1m, b0h, acc1, 0,0,0);\
        acc1 = __builtin_amdgcn_mfma_f32_32x32x16_bf16(a1h, b0m, acc1, 0,0,0);\
        acc1 = __builtin_amdgcn_mfma_f32_32x32x16_bf16(a1h, b0h, acc1, 0,0,0);\
    } } while (0)

    LOADSET(avA, bvA, 0);
    for (int it = 0; it < niters; it += 2) {
        if (it + 1 < niters) LOADSET(avB, bvB, it + 1);   // in flight across phases
        __syncthreads();                                  // prev MFMA done with LDS
        CONVWRITE(avA, bvA);
        __syncthreads();
        MFMAPHASE();
        if (it + 2 < niters) LOADSET(avA, bvA, it + 2);
        __syncthreads();
        CONVWRITE(avB, bvB);
        __syncthreads();
        MFMAPHASE();
    }

#undef LOADSET
#undef CONVWRITE
#undef MFMAPHASE

    // store partials
    const int col   = lane & 31;
    const int rbase = 4 * (lane >> 5);
    float* Pb = P + (size_t)s * T_STEPS * HTOT;
#pragma unroll
    for (int reg = 0; reg < 16; reg++) {
        const int row = (reg & 3) + rbase + 8 * (reg >> 2);
        const int t0  = wt + row;
        const int t1  = wt + 32 + row;
        const int h   = ht * BN + wh + col;
        if (t0 < T_STEPS) Pb[(size_t)t0 * HTOT + h] = acc0[reg];
        if (t1 < T_STEPS) Pb[(size_t)t1 * HTOT + h] = acc1[reg];
    }
}

// reduce partials + bias -> cur1[t][h]   (float4 per thread)
__global__ __launch_bounds__(256) void k_reduce(
    const float* __restrict__ P,
    const float* __restrict__ ab1, const float* __restrict__ cb1,
    float* __restrict__ cur1, int NS)
{
    int g4 = blockIdx.x * 256 + threadIdx.x;   // 0..12799
    int g  = g4 * 4;
    int h0 = g & (HTOT - 1);
    float4 sum;
    sum.x = (h0 + 0 < HID) ? ab1[h0 + 0] : cb1[h0 + 0 - HID];
    sum.y = (h0 + 1 < HID) ? ab1[h0 + 1] : cb1[h0 + 1 - HID];
    sum.z = (h0 + 2 < HID) ? ab1[h0 + 2] : cb1[h0 + 2 - HID];
    sum.w = (h0 + 3 < HID) ? ab1[h0 + 3] : cb1[h0 + 3 - HID];
    for (int ss = 0; ss < NS; ss++) {
        float4 v = *(const float4*)(P + (size_t)ss * T_STEPS * HTOT + g);
        sum.x += v.x; sum.y += v.y; sum.z += v.z; sum.w += v.w;
    }
    *(float4*)(cur1 + g) = sum;
}

// LIF1: 8 blocks x 64 threads, thread = neuron, 10-deep current prefetch.
__global__ __launch_bounds__(64) void k_lif1(
    const float* __restrict__ cur1,            // [100][512]
    unsigned long long* __restrict__ bitsws,   // [100][8]
    float* __restrict__ wsa)
{
    const int b    = blockIdx.x;   // 0..7
    const int lane = threadIdx.x;  // 0..63
    const int n    = b * 64 + lane;

    float mem = 0.f;
    for (int tb = 0; tb < T_STEPS; tb += 10) {
        float c[10];
#pragma unroll
        for (int i = 0; i < 10; i++) c[i] = cur1[(size_t)(tb + i) * HTOT + n];
#pragma unroll
        for (int i = 0; i < 10; i++) {
            float reset = (mem > THRESH) ? THRESH : 0.f;
            mem = BETA * mem + c[i] - reset;
            unsigned long long m = __ballot(mem > THRESH);
            if (lane == 0) bitsws[(size_t)(tb + i) * 8 + b] = m;
        }
    }
    if (b == 0 && lane == 0) { wsa[0] = 0.f; wsa[1] = 0.f; }  // zero accumulators
}

// GEMM2 + LIF2: block per output neuron j (0..19 actor, 20 critic).
// thread = timestep; W2 reads are LDS broadcasts.
__global__ __launch_bounds__(128) void k_gemm2(
    const unsigned long long* __restrict__ bitsws,  // [100][8]
    const float* __restrict__ aW2, const float* __restrict__ ab2,
    const float* __restrict__ cW2, const float* __restrict__ cb2,
    float* __restrict__ wsa, float* __restrict__ out)
{
    const int j   = blockIdx.x;    // 0..20
    const int tid = threadIdx.x;

    __shared__ float W[256];
    __shared__ float c2[T_STEPS];

    const float* Wsrc = (j < 20) ? (aW2 + j * 256) : cW2;
    for (int i = tid; i < 256; i += 128) W[i] = Wsrc[i];
    const float bias  = (j < 20) ? ab2[j] : cb2[0];
    const int   wbase = (j < 20) ? 0 : 4;
    __syncthreads();

    const int t = tid;
    if (t < T_STEPS) {
        unsigned long long m0 = bitsws[(size_t)t * 8 + wbase + 0];
        unsigned long long m1 = bitsws[(size_t)t * 8 + wbase + 1];
        unsigned long long m2 = bitsws[(size_t)t * 8 + wbase + 2];
        unsigned long long m3 = bitsws[(size_t)t * 8 + wbase + 3];
        float acc = bias;
#pragma unroll
        for (int bitp = 0; bitp < 64; bitp++) {
            acc += ((m0 >> bitp) & 1ULL) ? W[bitp]       : 0.f;
            acc += ((m1 >> bitp) & 1ULL) ? W[64 + bitp]  : 0.f;
            acc += ((m2 >> bitp) & 1ULL) ? W[128 + bitp] : 0.f;
            acc += ((m3 >> bitp) & 1ULL) ? W[192 + bitp] : 0.f;
        }
        c2[t] = acc;
    }
    __syncthreads();

    if (tid == 0) {
        float mem = 0.f, spk = 0.f;
        for (int tt = 0; tt < T_STEPS; tt++) {
            float reset = (mem > THRESH) ? THRESH : 0.f;
            mem = BETA * mem + c2[tt] - reset;
            spk += (mem > THRESH) ? 1.f : 0.f;
        }
        if (j < 10)       atomicAdd(&wsa[0], spk);   // exact: integer-valued floats
        else if (j < 20)  atomicAdd(&wsa[1], spk);
        else              out[2] = mem;              // critic final membrane
    }
}

__global__ __launch_bounds__(64) void k_final(
    const float* __restrict__ wsa, float* __restrict__ out)
{
    if (threadIdx.x == 0) {
        float a0 = wsa[0], a1 = wsa[1];
        float mx = fmaxf(a0, a1);
        float e0 = expf(a0 - mx), e1 = expf(a1 - mx);
        float inv = 1.f / (e0 + e1);
        out[0] = e0 * inv;
        out[1] = e1 * inv;
    }
}

extern "C" void kernel_launch(void* const* d_in, const int* in_sizes, int n_in,
                              void* d_out, int out_size, void* d_ws, size_t ws_size,
                              hipStream_t stream) {
    const float* x   = (const float*)d_in[0];
    const float* aW1 = (const float*)d_in[1];
    const float* ab1 = (const float*)d_in[2];
    const float* aW2 = (const float*)d_in[3];
    const float* ab2 = (const float*)d_in[4];
    const float* cW1 = (const float*)d_in[5];
    const float* cb1 = (const float*)d_in[6];
    const float* cW2 = (const float*)d_in[7];
    const float* cb2 = (const float*)d_in[8];
    float* out = (float*)d_out;

    int NS = 128;
    while (NS > 8 &&
           ((size_t)(NS + 1) * T_STEPS * HTOT) * sizeof(float) + 8192 > ws_size)
        NS >>= 1;
    int Kc = D_IN / NS;

    float* P    = (float*)d_ws;                                // [NS][100][512]
    float* cur1 = P + (size_t)NS * T_STEPS * HTOT;             // [100][512]
    unsigned long long* bitsws =
        (unsigned long long*)(cur1 + T_STEPS * HTOT);          // [100][8]
    float* wsa  = (float*)(bitsws + T_STEPS * 8);              // [2]

    k_gemm1 <<<dim3(4, NS), 512, 0, stream>>>(x, aW1, cW1, P, Kc);
    k_reduce<<<(T_STEPS * HTOT / 4) / 256, 256, 0, stream>>>(P, ab1, cb1, cur1, NS);
    k_lif1  <<<8, 64, 0, stream>>>(cur1, bitsws, wsa);
    k_gemm2 <<<21, 128, 0, stream>>>(bitsws, aW2, ab2, cW2, cb2, wsa, out);
    k_final <<<1, 64, 0, stream>>>(wsa, out);
}

// Round 4
// 105.273 us; speedup vs baseline: 2.2125x; 1.0546x over previous
//
#include <hip/hip_runtime.h>
#include <hip/hip_bf16.h>

#define T_STEPS 100
#define D_IN    65536
#define HID     256
#define HTOT    512
#define BETA    0.95f
#define THRESH  1.0f
#define CHUNK   256     // k columns per LDS stage
#define ROWS    128     // padded t rows

typedef __bf16 bf16x8 __attribute__((ext_vector_type(8)));
typedef float  f32x16 __attribute__((ext_vector_type(16)));

// GEMM1: x staged in LDS (bf16 hi/mid, swizzled), W streamed from global.
// 3-product split-precision MFMA. NO barriers in the inner loop.
// grid: (2 h-halves, NS k-splits), block 512 = 8 waves (2t x 4h), each 64x64.
__global__ __launch_bounds__(512) void k_gemm1(
    const float* __restrict__ x,     // [100][65536]
    const float* __restrict__ aW1,   // [256][65536]
    const float* __restrict__ cW1,   // [256][65536]
    float* __restrict__ P,           // [NS][100][512]
    int Kc)
{
    const int half = blockIdx.x;     // 0: actor rows, 1: critic rows
    const int s    = blockIdx.y;     // k-split
    const int tid  = threadIdx.x;
    const int lane = tid & 63;
    const int l31  = lane & 31;
    const int wv   = tid >> 6;           // 0..7
    const int wt   = (wv & 1) * 64;      // wave t-offset
    const int hq   = (wv >> 1) * 64;     // wave h-offset within the 256-half

    __shared__ __bf16 Ah[ROWS][CHUNK];   // 64 KB
    __shared__ __bf16 Am[ROWS][CHUNK];   // 64 KB

    const float* Wsrc = half ? cW1 : aW1;
    const float* w0 = Wsrc + (size_t)(hq + l31) * D_IN + (lane >> 5) * 8;  // q=0 row
    const float* w1 = w0 + (size_t)32 * D_IN;                              // q=1 row

    // staging coords: thread covers row sr, 64-float k-quarter skq
    const int sr  = tid >> 2;            // 0..127
    const int skq = tid & 3;             // 0..3
    const float* xrow = x + (size_t)sr * D_IN;

    f32x16 acc[2][2];
#pragma unroll
    for (int p = 0; p < 2; p++)
#pragma unroll
        for (int q = 0; q < 2; q++)
#pragma unroll
            for (int i = 0; i < 16; i++) acc[p][q][i] = 0.f;

    const int k0      = s * Kc;
    const int nchunks = Kc / CHUNK;

#define LOADB(d0, d0b, d1, d1b, sn) do {                                      \
    const float* p0_ = w0 + kb + (sn) * 16;                                   \
    const float* p1_ = w1 + kb + (sn) * 16;                                   \
    d0  = *(const float4*)(p0_);                                              \
    d0b = *(const float4*)(p0_ + 4);                                          \
    d1  = *(const float4*)(p1_);                                              \
    d1b = *(const float4*)(p1_ + 4);                                          \
} while (0)

#define STEP(c0, c0b, c1, c1b, sn) do {                                       \
    const int slot_ = (sn) * 2 + (lane >> 5);                                 \
    const int r0_ = wt + l31, r1_ = r0_ + 32;                                 \
    const int pe0_ = ((slot_ ^ (r0_ & 7)) << 3);                              \
    const int pe1_ = ((slot_ ^ (r1_ & 7)) << 3);                              \
    bf16x8 a0h = *(const bf16x8*)&Ah[r0_][pe0_];                              \
    bf16x8 a0m = *(const bf16x8*)&Am[r0_][pe0_];                              \
    bf16x8 a1h = *(const bf16x8*)&Ah[r1_][pe1_];                              \
    bf16x8 a1m = *(const bf16x8*)&Am[r1_][pe1_];                              \
    float f0_[8] = {c0.x, c0.y, c0.z, c0.w, c0b.x, c0b.y, c0b.z, c0b.w};      \
    float f1_[8] = {c1.x, c1.y, c1.z, c1.w, c1b.x, c1b.y, c1b.z, c1b.w};      \
    bf16x8 b0h, b0m, b1h, b1m;                                                \
    _Pragma("unroll")                                                         \
    for (int e = 0; e < 8; e++) {                                             \
        __bf16 h0 = (__bf16)f0_[e];                                           \
        b0h[e] = h0; b0m[e] = (__bf16)(f0_[e] - (float)h0);                   \
        __bf16 h1 = (__bf16)f1_[e];                                           \
        b1h[e] = h1; b1m[e] = (__bf16)(f1_[e] - (float)h1);                   \
    }                                                                         \
    acc[0][0] = __builtin_amdgcn_mfma_f32_32x32x16_bf16(a0m, b0h, acc[0][0], 0,0,0); \
    acc[0][0] = __builtin_amdgcn_mfma_f32_32x32x16_bf16(a0h, b0m, acc[0][0], 0,0,0); \
    acc[0][0] = __builtin_amdgcn_mfma_f32_32x32x16_bf16(a0h, b0h, acc[0][0], 0,0,0); \
    acc[0][1] = __builtin_amdgcn_mfma_f32_32x32x16_bf16(a0m, b1h, acc[0][1], 0,0,0); \
    acc[0][1] = __builtin_amdgcn_mfma_f32_32x32x16_bf16(a0h, b1m, acc[0][1], 0,0,0); \
    acc[0][1] = __builtin_amdgcn_mfma_f32_32x32x16_bf16(a0h, b1h, acc[0][1], 0,0,0); \
    acc[1][0] = __builtin_amdgcn_mfma_f32_32x32x16_bf16(a1m, b0h, acc[1][0], 0,0,0); \
    acc[1][0] = __builtin_amdgcn_mfma_f32_32x32x16_bf16(a1h, b0m, acc[1][0], 0,0,0); \
    acc[1][0] = __builtin_amdgcn_mfma_f32_32x32x16_bf16(a1h, b0h, acc[1][0], 0,0,0); \
    acc[1][1] = __builtin_amdgcn_mfma_f32_32x32x16_bf16(a1m, b1h, acc[1][1], 0,0,0); \
    acc[1][1] = __builtin_amdgcn_mfma_f32_32x32x16_bf16(a1h, b1m, acc[1][1], 0,0,0); \
    acc[1][1] = __builtin_amdgcn_mfma_f32_32x32x16_bf16(a1h, b1h, acc[1][1], 0,0,0); \
} while (0)

    for (int c = 0; c < nchunks; c++) {
        const int kb = k0 + c * CHUNK;
        if (c) __syncthreads();          // waves done reading previous chunk
        // ---- stage x chunk: fp32 -> bf16 hi/mid, swizzled
#pragma unroll
        for (int g = 0; g < 8; g++) {
            const int ko = skq * 64 + g * 8;
            float4 v0 = make_float4(0.f, 0.f, 0.f, 0.f), v1 = v0;
            if (sr < T_STEPS) {
                v0 = *(const float4*)(xrow + kb + ko);
                v1 = *(const float4*)(xrow + kb + ko + 4);
            }
            float f[8] = {v0.x, v0.y, v0.z, v0.w, v1.x, v1.y, v1.z, v1.w};
            bf16x8 hi, mi;
#pragma unroll
            for (int e = 0; e < 8; e++) {
                __bf16 h = (__bf16)f[e];
                hi[e] = h; mi[e] = (__bf16)(f[e] - (float)h);
            }
            const int slot = skq * 8 + g;
            const int pe   = ((slot ^ (sr & 7)) << 3);
            *(bf16x8*)&Ah[sr][pe] = hi;
            *(bf16x8*)&Am[sr][pe] = mi;
        }
        __syncthreads();

        // ---- W-stream: 16 k16-steps, B prefetched one step ahead, no barriers
        float4 bA0, bA0b, bA1, bA1b, bB0, bB0b, bB1, bB1b;
        LOADB(bA0, bA0b, bA1, bA1b, 0);
#pragma unroll
        for (int s2 = 0; s2 < 8; s2++) {
            const int s0 = 2 * s2, s1 = 2 * s2 + 1;
            LOADB(bB0, bB0b, bB1, bB1b, s1);
            STEP(bA0, bA0b, bA1, bA1b, s0);
            if (s1 < 15) LOADB(bA0, bA0b, bA1, bA1b, s1 + 1);
            STEP(bB0, bB0b, bB1, bB1b, s1);
        }
    }
#undef LOADB
#undef STEP

    // ---- store partials
    const int rbase = 4 * (lane >> 5);
    float* Pb = P + (size_t)s * T_STEPS * HTOT;
#pragma unroll
    for (int p = 0; p < 2; p++)
#pragma unroll
        for (int q = 0; q < 2; q++) {
            const int hcol = half * 256 + hq + q * 32 + l31;
#pragma unroll
            for (int reg = 0; reg < 16; reg++) {
                const int row = (reg & 3) + rbase + 8 * (reg >> 2);
                const int t   = wt + p * 32 + row;
                if (t < T_STEPS) Pb[(size_t)t * HTOT + hcol] = acc[p][q][reg];
            }
        }
}

// reduce partials + bias -> cur1[t][h]   (float4 per thread)
__global__ __launch_bounds__(256) void k_reduce(
    const float* __restrict__ P,
    const float* __restrict__ ab1, const float* __restrict__ cb1,
    float* __restrict__ cur1, int NS)
{
    int g4 = blockIdx.x * 256 + threadIdx.x;   // 0..12799
    int g  = g4 * 4;
    int h0 = g & (HTOT - 1);
    float4 sum;
    sum.x = (h0 + 0 < HID) ? ab1[h0 + 0] : cb1[h0 + 0 - HID];
    sum.y = (h0 + 1 < HID) ? ab1[h0 + 1] : cb1[h0 + 1 - HID];
    sum.z = (h0 + 2 < HID) ? ab1[h0 + 2] : cb1[h0 + 2 - HID];
    sum.w = (h0 + 3 < HID) ? ab1[h0 + 3] : cb1[h0 + 3 - HID];
    for (int ss = 0; ss < NS; ss++) {
        float4 v = *(const float4*)(P + (size_t)ss * T_STEPS * HTOT + g);
        sum.x += v.x; sum.y += v.y; sum.z += v.z; sum.w += v.w;
    }
    *(float4*)(cur1 + g) = sum;
}

// LIF1: 8 blocks x 64 threads, thread = neuron, 10-deep current prefetch.
__global__ __launch_bounds__(64) void k_lif1(
    const float* __restrict__ cur1,            // [100][512]
    unsigned long long* __restrict__ bitsws,   // [100][8]
    float* __restrict__ wsa)
{
    const int b    = blockIdx.x;   // 0..7
    const int lane = threadIdx.x;  // 0..63
    const int n    = b * 64 + lane;

    float mem = 0.f;
    for (int tb = 0; tb < T_STEPS; tb += 10) {
        float c[10];
#pragma unroll
        for (int i = 0; i < 10; i++) c[i] = cur1[(size_t)(tb + i) * HTOT + n];
#pragma unroll
        for (int i = 0; i < 10; i++) {
            float reset = (mem > THRESH) ? THRESH : 0.f;
            mem = BETA * mem + c[i] - reset;
            unsigned long long m = __ballot(mem > THRESH);
            if (lane == 0) bitsws[(size_t)(tb + i) * 8 + b] = m;
        }
    }
    if (b == 0 && lane == 0) { wsa[0] = 0.f; wsa[1] = 0.f; }
}

// GEMM2 + LIF2: block per output neuron j (0..19 actor, 20 critic).
__global__ __launch_bounds__(128) void k_gemm2(
    const unsigned long long* __restrict__ bitsws,  // [100][8]
    const float* __restrict__ aW2, const float* __restrict__ ab2,
    const float* __restrict__ cW2, const float* __restrict__ cb2,
    float* __restrict__ wsa, float* __restrict__ out)
{
    const int j   = blockIdx.x;    // 0..20
    const int tid = threadIdx.x;

    __shared__ float W[256];
    __shared__ float c2[T_STEPS];

    const float* Wsrc = (j < 20) ? (aW2 + j * 256) : cW2;
    for (int i = tid; i < 256; i += 128) W[i] = Wsrc[i];
    const float bias  = (j < 20) ? ab2[j] : cb2[0];
    const int   wbase = (j < 20) ? 0 : 4;
    __syncthreads();

    const int t = tid;
    if (t < T_STEPS) {
        unsigned long long m0 = bitsws[(size_t)t * 8 + wbase + 0];
        unsigned long long m1 = bitsws[(size_t)t * 8 + wbase + 1];
        unsigned long long m2 = bitsws[(size_t)t * 8 + wbase + 2];
        unsigned long long m3 = bitsws[(size_t)t * 8 + wbase + 3];
        float acc = bias;
#pragma unroll
        for (int bitp = 0; bitp < 64; bitp++) {
            acc += ((m0 >> bitp) & 1ULL) ? W[bitp]       : 0.f;
            acc += ((m1 >> bitp) & 1ULL) ? W[64 + bitp]  : 0.f;
            acc += ((m2 >> bitp) & 1ULL) ? W[128 + bitp] : 0.f;
            acc += ((m3 >> bitp) & 1ULL) ? W[192 + bitp] : 0.f;
        }
        c2[t] = acc;
    }
    __syncthreads();

    if (tid == 0) {
        float mem = 0.f, spk = 0.f;
        for (int tt = 0; tt < T_STEPS; tt++) {
            float reset = (mem > THRESH) ? THRESH : 0.f;
            mem = BETA * mem + c2[tt] - reset;
            spk += (mem > THRESH) ? 1.f : 0.f;
        }
        if (j < 10)       atomicAdd(&wsa[0], spk);   // exact: integer-valued floats
        else if (j < 20)  atomicAdd(&wsa[1], spk);
        else              out[2] = mem;
    }
}

__global__ __launch_bounds__(64) void k_final(
    const float* __restrict__ wsa, float* __restrict__ out)
{
    if (threadIdx.x == 0) {
        float a0 = wsa[0], a1 = wsa[1];
        float mx = fmaxf(a0, a1);
        float e0 = expf(a0 - mx), e1 = expf(a1 - mx);
        float inv = 1.f / (e0 + e1);
        out[0] = e0 * inv;
        out[1] = e1 * inv;
    }
}

extern "C" void kernel_launch(void* const* d_in, const int* in_sizes, int n_in,
                              void* d_out, int out_size, void* d_ws, size_t ws_size,
                              hipStream_t stream) {
    const float* x   = (const float*)d_in[0];
    const float* aW1 = (const float*)d_in[1];
    const float* ab1 = (const float*)d_in[2];
    const float* aW2 = (const float*)d_in[3];
    const float* ab2 = (const float*)d_in[4];
    const float* cW1 = (const float*)d_in[5];
    const float* cb1 = (const float*)d_in[6];
    const float* cW2 = (const float*)d_in[7];
    const float* cb2 = (const float*)d_in[8];
    float* out = (float*)d_out;

    int NS = 128;
    while (NS > 8 &&
           ((size_t)(NS + 1) * T_STEPS * HTOT) * sizeof(float) + 8192 > ws_size)
        NS >>= 1;
    int Kc = D_IN / NS;   // multiple of CHUNK for NS in {8..256}

    float* P    = (float*)d_ws;                                // [NS][100][512]
    float* cur1 = P + (size_t)NS * T_STEPS * HTOT;             // [100][512]
    unsigned long long* bitsws =
        (unsigned long long*)(cur1 + T_STEPS * HTOT);          // [100][8]
    float* wsa  = (float*)(bitsws + T_STEPS * 8);              // [2]

    k_gemm1 <<<dim3(2, NS), 512, 0, stream>>>(x, aW1, cW1, P, Kc);
    k_reduce<<<(T_STEPS * HTOT / 4) / 256, 256, 0, stream>>>(P, ab1, cb1, cur1, NS);
    k_lif1  <<<8, 64, 0, stream>>>(cur1, bitsws, wsa);
    k_gemm2 <<<21, 128, 0, stream>>>(bitsws, aW2, ab2, cW2, cb2, wsa, out);
    k_final <<<1, 64, 0, stream>>>(wsa, out);
}

// Round 5
// 99.074 us; speedup vs baseline: 2.3509x; 1.0626x over previous
//
#include <hip/hip_runtime.h>
#include <hip/hip_bf16.h>

#define T_STEPS 100
#define D_IN    65536
#define HID     256
#define HTOT    512
#define BETA    0.95f
#define THRESH  1.0f
#define CHUNK   256     // k columns per LDS stage
#define ROWS    128     // padded t rows

typedef __bf16 bf16x8 __attribute__((ext_vector_type(8)));
typedef float  f32x16 __attribute__((ext_vector_type(16)));

// GEMM1: x staged in LDS (bf16 hi/mid, swizzled), W streamed from global.
// 3-product split-precision MFMA; k-order identical to prior rounds (bitwise).
// grid: (2 h-halves, NS k-splits), block 1024 = 16 waves, wave = 64t x 32h.
// 128KB LDS -> 1 block/CU, but 16 waves -> 4 waves/SIMD for latency hiding.
__global__ __launch_bounds__(1024, 4) void k_gemm1(
    const float* __restrict__ x,     // [100][65536]
    const float* __restrict__ aW1,   // [256][65536]
    const float* __restrict__ cW1,   // [256][65536]
    float* __restrict__ P,           // [NS][100][512]
    int Kc)
{
    const int half = blockIdx.x;     // 0: actor rows, 1: critic rows
    const int s    = blockIdx.y;     // k-split
    const int tid  = threadIdx.x;
    const int lane = tid & 63;
    const int l31  = lane & 31;
    const int wv   = tid >> 6;           // 0..15
    const int wt   = (wv & 1) * 64;      // wave t-offset
    const int hq   = (wv >> 1) * 32;     // wave h-offset within the 256-half

    __shared__ __bf16 Ah[ROWS][CHUNK];   // 64 KB
    __shared__ __bf16 Am[ROWS][CHUNK];   // 64 KB

    const float* Wsrc = half ? cW1 : aW1;
    const float* w0 = Wsrc + (size_t)(hq + l31) * D_IN + (lane >> 5) * 8;

    // staging coords: thread covers row sr, 8-float groups at (tid&7)*8 + j*64
    const int sr = tid >> 3;             // 0..127
    const float* xrow = x + (size_t)sr * D_IN + (tid & 7) * 8;
    const bool xok = (sr < T_STEPS);

    f32x16 acc0, acc1;
#pragma unroll
    for (int i = 0; i < 16; i++) { acc0[i] = 0.f; acc1[i] = 0.f; }

    const int k0      = s * Kc;
    const int nchunks = Kc / CHUNK;

    for (int c = 0; c < nchunks; c++) {
        const int kb = k0 + c * CHUNK;
        if (c) __syncthreads();          // waves done reading previous chunk
        // ---- stage x chunk: fp32 -> bf16 hi/mid, swizzled
#pragma unroll
        for (int j = 0; j < 4; j++) {
            float4 v0 = make_float4(0.f, 0.f, 0.f, 0.f), v1 = v0;
            if (xok) {
                v0 = *(const float4*)(xrow + kb + j * 64);
                v1 = *(const float4*)(xrow + kb + j * 64 + 4);
            }
            float f[8] = {v0.x, v0.y, v0.z, v0.w, v1.x, v1.y, v1.z, v1.w};
            bf16x8 hi, mi;
#pragma unroll
            for (int e = 0; e < 8; e++) {
                __bf16 h = (__bf16)f[e];
                hi[e] = h; mi[e] = (__bf16)(f[e] - (float)h);
            }
            const int slot = (tid & 7) + j * 8;
            const int pe   = ((slot ^ (sr & 7)) << 3);
            *(bf16x8*)&Ah[sr][pe] = hi;
            *(bf16x8*)&Am[sr][pe] = mi;
        }
        __syncthreads();

        // ---- W-stream: 16 k16-steps, rotating 3-buffer depth-2 prefetch,
        //      no barriers. Buffer indices are compile-time after full unroll.
        float4 bd0[3], bd1[3];
#define LOADB(i, sn) do {                                                     \
    const float* p_ = w0 + kb + (sn) * 16;                                    \
    bd0[i] = *(const float4*)p_;                                              \
    bd1[i] = *(const float4*)(p_ + 4);                                        \
} while (0)
        LOADB(0, 0);
        LOADB(1, 1);
#pragma unroll
        for (int s16 = 0; s16 < 16; s16++) {
            if (s16 + 2 < 16) LOADB((s16 + 2) % 3, s16 + 2);
            const int bi = s16 % 3;
            // convert B fragment (hi/mid)
            float f0_[8] = {bd0[bi].x, bd0[bi].y, bd0[bi].z, bd0[bi].w,
                            bd1[bi].x, bd1[bi].y, bd1[bi].z, bd1[bi].w};
            bf16x8 bh, bm;
#pragma unroll
            for (int e = 0; e < 8; e++) {
                __bf16 h = (__bf16)f0_[e];
                bh[e] = h; bm[e] = (__bf16)(f0_[e] - (float)h);
            }
            // A fragments from LDS (swizzled)
            const int slot = s16 * 2 + (lane >> 5);
            const int r0 = wt + l31, r1 = r0 + 32;
            const int pe0 = ((slot ^ (r0 & 7)) << 3);
            const int pe1 = ((slot ^ (r1 & 7)) << 3);
            bf16x8 a0h = *(const bf16x8*)&Ah[r0][pe0];
            bf16x8 a0m = *(const bf16x8*)&Am[r0][pe0];
            bf16x8 a1h = *(const bf16x8*)&Ah[r1][pe1];
            bf16x8 a1m = *(const bf16x8*)&Am[r1][pe1];
            acc0 = __builtin_amdgcn_mfma_f32_32x32x16_bf16(a0m, bh, acc0, 0, 0, 0);
            acc0 = __builtin_amdgcn_mfma_f32_32x32x16_bf16(a0h, bm, acc0, 0, 0, 0);
            acc0 = __builtin_amdgcn_mfma_f32_32x32x16_bf16(a0h, bh, acc0, 0, 0, 0);
            acc1 = __builtin_amdgcn_mfma_f32_32x32x16_bf16(a1m, bh, acc1, 0, 0, 0);
            acc1 = __builtin_amdgcn_mfma_f32_32x32x16_bf16(a1h, bm, acc1, 0, 0, 0);
            acc1 = __builtin_amdgcn_mfma_f32_32x32x16_bf16(a1h, bh, acc1, 0, 0, 0);
        }
#undef LOADB
    }

    // ---- store partials
    const int rbase = 4 * (lane >> 5);
    const int hcol  = half * 256 + hq + l31;
    float* Pb = P + (size_t)s * T_STEPS * HTOT;
#pragma unroll
    for (int reg = 0; reg < 16; reg++) {
        const int row = (reg & 3) + rbase + 8 * (reg >> 2);
        const int t0  = wt + row;
        const int t1  = wt + 32 + row;
        if (t0 < T_STEPS) Pb[(size_t)t0 * HTOT + hcol] = acc0[reg];
        if (t1 < T_STEPS) Pb[(size_t)t1 * HTOT + hcol] = acc1[reg];
    }
}

// reduce partials + bias -> cur1[t][h]   (float4 per thread)
__global__ __launch_bounds__(256) void k_reduce(
    const float* __restrict__ P,
    const float* __restrict__ ab1, const float* __restrict__ cb1,
    float* __restrict__ cur1, int NS)
{
    int g4 = blockIdx.x * 256 + threadIdx.x;   // 0..12799
    int g  = g4 * 4;
    int h0 = g & (HTOT - 1);
    float4 sum;
    sum.x = (h0 + 0 < HID) ? ab1[h0 + 0] : cb1[h0 + 0 - HID];
    sum.y = (h0 + 1 < HID) ? ab1[h0 + 1] : cb1[h0 + 1 - HID];
    sum.z = (h0 + 2 < HID) ? ab1[h0 + 2] : cb1[h0 + 2 - HID];
    sum.w = (h0 + 3 < HID) ? ab1[h0 + 3] : cb1[h0 + 3 - HID];
    for (int ss = 0; ss < NS; ss++) {
        float4 v = *(const float4*)(P + (size_t)ss * T_STEPS * HTOT + g);
        sum.x += v.x; sum.y += v.y; sum.z += v.z; sum.w += v.w;
    }
    *(float4*)(cur1 + g) = sum;
}

// LIF1: 8 blocks x 64 threads, thread = neuron, 10-deep current prefetch.
__global__ __launch_bounds__(64) void k_lif1(
    const float* __restrict__ cur1,            // [100][512]
    unsigned long long* __restrict__ bitsws,   // [100][8]
    float* __restrict__ wsa)
{
    const int b    = blockIdx.x;   // 0..7
    const int lane = threadIdx.x;  // 0..63
    const int n    = b * 64 + lane;

    float mem = 0.f;
    for (int tb = 0; tb < T_STEPS; tb += 10) {
        float c[10];
#pragma unroll
        for (int i = 0; i < 10; i++) c[i] = cur1[(size_t)(tb + i) * HTOT + n];
#pragma unroll
        for (int i = 0; i < 10; i++) {
            float reset = (mem > THRESH) ? THRESH : 0.f;
            mem = BETA * mem + c[i] - reset;
            unsigned long long m = __ballot(mem > THRESH);
            if (lane == 0) bitsws[(size_t)(tb + i) * 8 + b] = m;
        }
    }
    if (b == 0 && lane == 0) { wsa[0] = 0.f; wsa[1] = 0.f; }
}

// GEMM2 + LIF2: block per output neuron j (0..19 actor, 20 critic).
__global__ __launch_bounds__(128) void k_gemm2(
    const unsigned long long* __restrict__ bitsws,  // [100][8]
    const float* __restrict__ aW2, const float* __restrict__ ab2,
    const float* __restrict__ cW2, const float* __restrict__ cb2,
    float* __restrict__ wsa, float* __restrict__ out)
{
    const int j   = blockIdx.x;    // 0..20
    const int tid = threadIdx.x;

    __shared__ float W[256];
    __shared__ float c2[T_STEPS];

    const float* Wsrc = (j < 20) ? (aW2 + j * 256) : cW2;
    for (int i = tid; i < 256; i += 128) W[i] = Wsrc[i];
    const float bias  = (j < 20) ? ab2[j] : cb2[0];
    const int   wbase = (j < 20) ? 0 : 4;
    __syncthreads();

    const int t = tid;
    if (t < T_STEPS) {
        unsigned long long m0 = bitsws[(size_t)t * 8 + wbase + 0];
        unsigned long long m1 = bitsws[(size_t)t * 8 + wbase + 1];
        unsigned long long m2 = bitsws[(size_t)t * 8 + wbase + 2];
        unsigned long long m3 = bitsws[(size_t)t * 8 + wbase + 3];
        float acc = bias;
#pragma unroll
        for (int bitp = 0; bitp < 64; bitp++) {
            acc += ((m0 >> bitp) & 1ULL) ? W[bitp]       : 0.f;
            acc += ((m1 >> bitp) & 1ULL) ? W[64 + bitp]  : 0.f;
            acc += ((m2 >> bitp) & 1ULL) ? W[128 + bitp] : 0.f;
            acc += ((m3 >> bitp) & 1ULL) ? W[192 + bitp] : 0.f;
        }
        c2[t] = acc;
    }
    __syncthreads();

    if (tid == 0) {
        float mem = 0.f, spk = 0.f;
        for (int tt = 0; tt < T_STEPS; tt++) {
            float reset = (mem > THRESH) ? THRESH : 0.f;
            mem = BETA * mem + c2[tt] - reset;
            spk += (mem > THRESH) ? 1.f : 0.f;
        }
        if (j < 10)       atomicAdd(&wsa[0], spk);   // exact: integer-valued floats
        else if (j < 20)  atomicAdd(&wsa[1], spk);
        else              out[2] = mem;
    }
}

__global__ __launch_bounds__(64) void k_final(
    const float* __restrict__ wsa, float* __restrict__ out)
{
    if (threadIdx.x == 0) {
        float a0 = wsa[0], a1 = wsa[1];
        float mx = fmaxf(a0, a1);
        float e0 = expf(a0 - mx), e1 = expf(a1 - mx);
        float inv = 1.f / (e0 + e1);
        out[0] = e0 * inv;
        out[1] = e1 * inv;
    }
}

extern "C" void kernel_launch(void* const* d_in, const int* in_sizes, int n_in,
                              void* d_out, int out_size, void* d_ws, size_t ws_size,
                              hipStream_t stream) {
    const float* x   = (const float*)d_in[0];
    const float* aW1 = (const float*)d_in[1];
    const float* ab1 = (const float*)d_in[2];
    const float* aW2 = (const float*)d_in[3];
    const float* ab2 = (const float*)d_in[4];
    const float* cW1 = (const float*)d_in[5];
    const float* cb1 = (const float*)d_in[6];
    const float* cW2 = (const float*)d_in[7];
    const float* cb2 = (const float*)d_in[8];
    float* out = (float*)d_out;

    int NS = 128;
    while (NS > 8 &&
           ((size_t)(NS + 1) * T_STEPS * HTOT) * sizeof(float) + 8192 > ws_size)
        NS >>= 1;
    int Kc = D_IN / NS;   // multiple of CHUNK for NS in {8..256}

    float* P    = (float*)d_ws;                                // [NS][100][512]
    float* cur1 = P + (size_t)NS * T_STEPS * HTOT;             // [100][512]
    unsigned long long* bitsws =
        (unsigned long long*)(cur1 + T_STEPS * HTOT);          // [100][8]
    float* wsa  = (float*)(bitsws + T_STEPS * 8);              // [2]

    k_gemm1 <<<dim3(2, NS), 1024, 0, stream>>>(x, aW1, cW1, P, Kc);
    k_reduce<<<(T_STEPS * HTOT / 4) / 256, 256, 0, stream>>>(P, ab1, cb1, cur1, NS);
    k_lif1  <<<8, 64, 0, stream>>>(cur1, bitsws, wsa);
    k_gemm2 <<<21, 128, 0, stream>>>(bitsws, aW2, ab2, cW2, cb2, wsa, out);
    k_final <<<1, 64, 0, stream>>>(wsa, out);
}

// Round 6
// 97.173 us; speedup vs baseline: 2.3969x; 1.0196x over previous
//
#include <hip/hip_runtime.h>
#include <hip/hip_bf16.h>

#define T_STEPS 100
#define D_IN    65536
#define HID     256
#define HTOT    512
#define BETA    0.95f
#define THRESH  1.0f
#define CHUNK   64      // k columns per x-stage chunk (2 BK-steps of 32)
#define ROWS    128     // padded t rows

typedef __bf16 bf16x8 __attribute__((ext_vector_type(8)));
typedef float  f32x16 __attribute__((ext_vector_type(16)));

__device__ __forceinline__ void gload_lds16(const float* g, void* l) {
    __builtin_amdgcn_global_load_lds(
        (const __attribute__((address_space(1))) void*)g,
        (__attribute__((address_space(3))) void*)l, 16, 0, 0);
}

// GEMM1: x in LDS (bf16 hi/mid, XOR-swizzled), W double-buffered fp32 in LDS
// via global_load_lds (pre-swizzled global source), raw s_barrier + manual
// vmcnt. 3-product split-precision MFMA, k-order bitwise-identical to R5.
// grid: (4 h-tiles of 128, NS k-splits), block 512 = 8 waves (2t x 4h, 64x32).
__global__ __launch_bounds__(512, 4) void k_gemm1(
    const float* __restrict__ x,     // [100][65536]
    const float* __restrict__ aW1,   // [256][65536]
    const float* __restrict__ cW1,   // [256][65536]
    float* __restrict__ P,           // [NS][100][512]
    int Kc)
{
    const int ht   = blockIdx.x;     // 0..3 (h-rows [ht*128, ht*128+128))
    const int s    = blockIdx.y;     // k-split
    const int tid  = threadIdx.x;
    const int lane = tid & 63;
    const int l31  = lane & 31;
    const int wv   = tid >> 6;           // 0..7
    const int wt   = (wv & 1) * 64;      // wave t-offset
    const int hq   = (wv >> 1) * 32;     // wave h-offset within the 128-tile

    __shared__ __bf16 Ah[ROWS][CHUNK];   // 16 KB
    __shared__ __bf16 Am[ROWS][CHUNK];   // 16 KB
    __shared__ float  Wf[2][128][32];    // 32 KB (double-buffered W BK-tile)

    const float* Wbase = (ht < 2) ? (aW1 + (size_t)ht * 128 * D_IN)
                                  : (cW1 + (size_t)(ht - 2) * 128 * D_IN);

    // ---- W staging map: granule gi covers (row = gi>>3, g = gi&7) of the
    // [128][32] fp32 tile. LDS dest is linear (wave-uniform base + lane*16);
    // bank-conflict swizzle applied on the GLOBAL source (g_src = g ^ (row&7)).
    const int gi0   = wv * 64 + lane;          // op 0; op 1 = gi0 + 512
    const int wrow0 = gi0 >> 3,          wg0 = gi0 & 7;
    const int wrow1 = (gi0 + 512) >> 3,  wg1 = (gi0 + 512) & 7;
    const float* wsrc0 = Wbase + (size_t)wrow0 * D_IN + ((wg0 ^ (wrow0 & 7)) * 4);
    const float* wsrc1 = Wbase + (size_t)wrow1 * D_IN + ((wg1 ^ (wrow1 & 7)) * 4);
    char* WfB = (char*)&Wf[0][0][0];

#define WSTAGE(buf, kflt) do {                                                \
    gload_lds16(wsrc0 + (kflt), WfB + (buf) * 16384 + gi0 * 16);              \
    gload_lds16(wsrc1 + (kflt), WfB + (buf) * 16384 + 8192 + gi0 * 16);       \
} while (0)

    // ---- x staging coords: thread covers row sr, 16 floats at gq*16
    const int sr = tid >> 2;             // 0..127
    const int gq = tid & 3;              // 0..3
    const float* xrow = x + (size_t)sr * D_IN + gq * 16;
    const bool xok = (sr < T_STEPS);

#define XSTAGE(kflt) do {                                                     \
    _Pragma("unroll")                                                         \
    for (int j = 0; j < 2; j++) {                                             \
        float4 v0 = make_float4(0.f, 0.f, 0.f, 0.f), v1 = v0;                 \
        if (xok) {                                                            \
            v0 = *(const float4*)(xrow + (kflt) + j * 8);                     \
            v1 = *(const float4*)(xrow + (kflt) + j * 8 + 4);                 \
        }                                                                     \
        float f[8] = {v0.x, v0.y, v0.z, v0.w, v1.x, v1.y, v1.z, v1.w};        \
        bf16x8 hi, mi;                                                        \
        _Pragma("unroll")                                                     \
        for (int e = 0; e < 8; e++) {                                         \
            __bf16 h = (__bf16)f[e];                                          \
            hi[e] = h; mi[e] = (__bf16)(f[e] - (float)h);                     \
        }                                                                     \
        const int slot = gq * 2 + j;                                          \
        const int pe   = ((slot ^ (sr & 7)) << 3);                            \
        *(bf16x8*)&Ah[sr][pe] = hi;                                           \
        *(bf16x8*)&Am[sr][pe] = mi;                                           \
    }                                                                         \
} while (0)

    f32x16 acc0, acc1;
#pragma unroll
    for (int i = 0; i < 16; i++) { acc0[i] = 0.f; acc1[i] = 0.f; }

#define COMPUTE(buf, bk) do {                                                 \
    _Pragma("unroll")                                                         \
    for (int s16 = 0; s16 < 2; s16++) {                                       \
        const int hr = hq + l31;                                              \
        const int gb = s16 * 4 + (lane >> 5) * 2;                             \
        const int g0 = (gb ^ (hr & 7));                                       \
        const int g1 = ((gb + 1) ^ (hr & 7));                                 \
        float4 wa = *(const float4*)&Wf[buf][hr][g0 * 4];                     \
        float4 wb = *(const float4*)&Wf[buf][hr][g1 * 4];                     \
        float fb[8] = {wa.x, wa.y, wa.z, wa.w, wb.x, wb.y, wb.z, wb.w};       \
        bf16x8 bh, bm;                                                        \
        _Pragma("unroll")                                                     \
        for (int e = 0; e < 8; e++) {                                         \
            __bf16 h = (__bf16)fb[e];                                         \
            bh[e] = h; bm[e] = (__bf16)(fb[e] - (float)h);                    \
        }                                                                     \
        const int slot = (bk) * 4 + s16 * 2 + (lane >> 5);                    \
        const int r0 = wt + l31, r1 = r0 + 32;                                \
        const int pe0 = ((slot ^ (r0 & 7)) << 3);                             \
        const int pe1 = ((slot ^ (r1 & 7)) << 3);                             \
        bf16x8 a0h = *(const bf16x8*)&Ah[r0][pe0];                            \
        bf16x8 a0m = *(const bf16x8*)&Am[r0][pe0];                            \
        bf16x8 a1h = *(const bf16x8*)&Ah[r1][pe1];                            \
        bf16x8 a1m = *(const bf16x8*)&Am[r1][pe1];                            \
        acc0 = __builtin_amdgcn_mfma_f32_32x32x16_bf16(a0m, bh, acc0, 0,0,0); \
        acc0 = __builtin_amdgcn_mfma_f32_32x32x16_bf16(a0h, bm, acc0, 0,0,0); \
        acc0 = __builtin_amdgcn_mfma_f32_32x32x16_bf16(a0h, bh, acc0, 0,0,0); \
        acc1 = __builtin_amdgcn_mfma_f32_32x32x16_bf16(a1m, bh, acc1, 0,0,0); \
        acc1 = __builtin_amdgcn_mfma_f32_32x32x16_bf16(a1h, bm, acc1, 0,0,0); \
        acc1 = __builtin_amdgcn_mfma_f32_32x32x16_bf16(a1h, bh, acc1, 0,0,0); \
    }                                                                         \
} while (0)

    const int k0      = s * Kc;
    const int nchunks = Kc / CHUNK;

    WSTAGE(0, k0);                            // prologue: chunk 0, bk 0
    for (int c = 0; c < nchunks; c++) {
        const int kc = k0 + c * CHUNK;
        // ---- step bk=0 (chunk start)
        asm volatile("s_waitcnt vmcnt(0)" ::: "memory");   // Wf[0] ready
        __builtin_amdgcn_s_barrier();                      // prev compute done
        __builtin_amdgcn_sched_barrier(0);
        XSTAGE(kc);                                        // overwrite Ah/Am
        asm volatile("s_waitcnt lgkmcnt(0)" ::: "memory");
        __builtin_amdgcn_s_barrier();
        __builtin_amdgcn_sched_barrier(0);
        WSTAGE(1, kc + 32);                                // next BK in flight
        COMPUTE(0, 0);
        // ---- step bk=1
        asm volatile("s_waitcnt vmcnt(0)" ::: "memory");   // Wf[1] ready
        __builtin_amdgcn_s_barrier();                      // Wf[0] readers done
        __builtin_amdgcn_sched_barrier(0);
        if (c + 1 < nchunks) WSTAGE(0, kc + CHUNK);        // next chunk bk 0
        COMPUTE(1, 1);
    }
#undef WSTAGE
#undef XSTAGE
#undef COMPUTE

    // ---- store partials
    const int rbase = 4 * (lane >> 5);
    const int hcol  = ht * 128 + hq + l31;
    float* Pb = P + (size_t)s * T_STEPS * HTOT;
#pragma unroll
    for (int reg = 0; reg < 16; reg++) {
        const int row = (reg & 3) + rbase + 8 * (reg >> 2);
        const int t0  = wt + row;
        const int t1  = wt + 32 + row;
        if (t0 < T_STEPS) Pb[(size_t)t0 * HTOT + hcol] = acc0[reg];
        if (t1 < T_STEPS) Pb[(size_t)t1 * HTOT + hcol] = acc1[reg];
    }
}

// reduce partials + bias -> cur1[t][h]   (float4 per thread)
__global__ __launch_bounds__(256) void k_reduce(
    const float* __restrict__ P,
    const float* __restrict__ ab1, const float* __restrict__ cb1,
    float* __restrict__ cur1, int NS)
{
    int g4 = blockIdx.x * 256 + threadIdx.x;   // 0..12799
    int g  = g4 * 4;
    int h0 = g & (HTOT - 1);
    float4 sum;
    sum.x = (h0 + 0 < HID) ? ab1[h0 + 0] : cb1[h0 + 0 - HID];
    sum.y = (h0 + 1 < HID) ? ab1[h0 + 1] : cb1[h0 + 1 - HID];
    sum.z = (h0 + 2 < HID) ? ab1[h0 + 2] : cb1[h0 + 2 - HID];
    sum.w = (h0 + 3 < HID) ? ab1[h0 + 3] : cb1[h0 + 3 - HID];
    for (int ss = 0; ss < NS; ss++) {
        float4 v = *(const float4*)(P + (size_t)ss * T_STEPS * HTOT + g);
        sum.x += v.x; sum.y += v.y; sum.z += v.z; sum.w += v.w;
    }
    *(float4*)(cur1 + g) = sum;
}

// LIF1: 8 blocks x 64 threads, thread = neuron, 10-deep current prefetch.
__global__ __launch_bounds__(64) void k_lif1(
    const float* __restrict__ cur1,            // [100][512]
    unsigned long long* __restrict__ bitsws,   // [100][8]
    float* __restrict__ wsa)
{
    const int b    = blockIdx.x;   // 0..7
    const int lane = threadIdx.x;  // 0..63
    const int n    = b * 64 + lane;

    float mem = 0.f;
    for (int tb = 0; tb < T_STEPS; tb += 10) {
        float c[10];
#pragma unroll
        for (int i = 0; i < 10; i++) c[i] = cur1[(size_t)(tb + i) * HTOT + n];
#pragma unroll
        for (int i = 0; i < 10; i++) {
            float reset = (mem > THRESH) ? THRESH : 0.f;
            mem = BETA * mem + c[i] - reset;
            unsigned long long m = __ballot(mem > THRESH);
            if (lane == 0) bitsws[(size_t)(tb + i) * 8 + b] = m;
        }
    }
    if (b == 0 && lane == 0) { wsa[0] = 0.f; wsa[1] = 0.f; }
}

// GEMM2 + LIF2: block per output neuron j (0..19 actor, 20 critic).
__global__ __launch_bounds__(128) void k_gemm2(
    const unsigned long long* __restrict__ bitsws,  // [100][8]
    const float* __restrict__ aW2, const float* __restrict__ ab2,
    const float* __restrict__ cW2, const float* __restrict__ cb2,
    float* __restrict__ wsa, float* __restrict__ out)
{
    const int j   = blockIdx.x;    // 0..20
    const int tid = threadIdx.x;

    __shared__ float W[256];
    __shared__ float c2[T_STEPS];

    const float* Wsrc = (j < 20) ? (aW2 + j * 256) : cW2;
    for (int i = tid; i < 256; i += 128) W[i] = Wsrc[i];
    const float bias  = (j < 20) ? ab2[j] : cb2[0];
    const int   wbase = (j < 20) ? 0 : 4;
    __syncthreads();

    const int t = tid;
    if (t < T_STEPS) {
        unsigned long long m0 = bitsws[(size_t)t * 8 + wbase + 0];
        unsigned long long m1 = bitsws[(size_t)t * 8 + wbase + 1];
        unsigned long long m2 = bitsws[(size_t)t * 8 + wbase + 2];
        unsigned long long m3 = bitsws[(size_t)t * 8 + wbase + 3];
        float acc = bias;
#pragma unroll
        for (int bitp = 0; bitp < 64; bitp++) {
            acc += ((m0 >> bitp) & 1ULL) ? W[bitp]       : 0.f;
            acc += ((m1 >> bitp) & 1ULL) ? W[64 + bitp]  : 0.f;
            acc += ((m2 >> bitp) & 1ULL) ? W[128 + bitp] : 0.f;
            acc += ((m3 >> bitp) & 1ULL) ? W[192 + bitp] : 0.f;
        }
        c2[t] = acc;
    }
    __syncthreads();

    if (tid == 0) {
        float mem = 0.f, spk = 0.f;
        for (int tt = 0; tt < T_STEPS; tt++) {
            float reset = (mem > THRESH) ? THRESH : 0.f;
            mem = BETA * mem + c2[tt] - reset;
            spk += (mem > THRESH) ? 1.f : 0.f;
        }
        if (j < 10)       atomicAdd(&wsa[0], spk);   // exact: integer-valued floats
        else if (j < 20)  atomicAdd(&wsa[1], spk);
        else              out[2] = mem;
    }
}

__global__ __launch_bounds__(64) void k_final(
    const float* __restrict__ wsa, float* __restrict__ out)
{
    if (threadIdx.x == 0) {
        float a0 = wsa[0], a1 = wsa[1];
        float mx = fmaxf(a0, a1);
        float e0 = expf(a0 - mx), e1 = expf(a1 - mx);
        float inv = 1.f / (e0 + e1);
        out[0] = e0 * inv;
        out[1] = e1 * inv;
    }
}

extern "C" void kernel_launch(void* const* d_in, const int* in_sizes, int n_in,
                              void* d_out, int out_size, void* d_ws, size_t ws_size,
                              hipStream_t stream) {
    const float* x   = (const float*)d_in[0];
    const float* aW1 = (const float*)d_in[1];
    const float* ab1 = (const float*)d_in[2];
    const float* aW2 = (const float*)d_in[3];
    const float* ab2 = (const float*)d_in[4];
    const float* cW1 = (const float*)d_in[5];
    const float* cb1 = (const float*)d_in[6];
    const float* cW2 = (const float*)d_in[7];
    const float* cb2 = (const float*)d_in[8];
    float* out = (float*)d_out;

    int NS = 128;
    while (NS > 8 &&
           ((size_t)(NS + 1) * T_STEPS * HTOT) * sizeof(float) + 8192 > ws_size)
        NS >>= 1;
    int Kc = D_IN / NS;   // multiple of CHUNK for NS in {8..256}

    float* P    = (float*)d_ws;                                // [NS][100][512]
    float* cur1 = P + (size_t)NS * T_STEPS * HTOT;             // [100][512]
    unsigned long long* bitsws =
        (unsigned long long*)(cur1 + T_STEPS * HTOT);          // [100][8]
    float* wsa  = (float*)(bitsws + T_STEPS * 8);              // [2]

    k_gemm1 <<<dim3(4, NS), 512, 0, stream>>>(x, aW1, cW1, P, Kc);
    k_reduce<<<(T_STEPS * HTOT / 4) / 256, 256, 0, stream>>>(P, ab1, cb1, cur1, NS);
    k_lif1  <<<8, 64, 0, stream>>>(cur1, bitsws, wsa);
    k_gemm2 <<<21, 128, 0, stream>>>(bitsws, aW2, ab2, cW2, cb2, wsa, out);
    k_final <<<1, 64, 0, stream>>>(wsa, out);
}

// Round 7
// 94.289 us; speedup vs baseline: 2.4702x; 1.0306x over previous
//
#include <hip/hip_runtime.h>
#include <hip/hip_bf16.h>

#define T_STEPS 100
#define D_IN    65536
#define HID     256
#define HTOT    512
#define BETA    0.95f
#define THRESH  1.0f

typedef __bf16 bf16x8 __attribute__((ext_vector_type(8)));
typedef float  f32x16 __attribute__((ext_vector_type(16)));

__device__ __forceinline__ void gload_lds16(const void* g, void* l) {
    __builtin_amdgcn_global_load_lds(
        (const __attribute__((address_space(1))) void*)g,
        (__attribute__((address_space(3))) void*)l, 16, 0, 0);
}

// ---- x pre-pack: fp32 -> bf16 hi/mid blobs, one 16-KB blob per global
// 32-k-column block gk (2048 blobs). Blob layout == gemm1's LDS layout:
// granule G(r,slot) = r*4 + (slot ^ ((r>>1)&3)), hi at G*16, mid at 8 KB + G*16.
// Rows 100..127 zero-padded.
__global__ __launch_bounds__(512) void k_xpack(
    const float* __restrict__ x, __bf16* __restrict__ xp)
{
    const int idx  = blockIdx.x * 512 + threadIdx.x;  // over [gk][r][slot]
    const int slot = idx & 3;
    const int r    = (idx >> 2) & 127;
    const int gk   = idx >> 9;

    float f[8] = {0.f, 0.f, 0.f, 0.f, 0.f, 0.f, 0.f, 0.f};
    if (r < T_STEPS) {
        const float* src = x + (size_t)r * D_IN + gk * 32 + slot * 8;
        float4 v0 = *(const float4*)src;
        float4 v1 = *(const float4*)(src + 4);
        f[0] = v0.x; f[1] = v0.y; f[2] = v0.z; f[3] = v0.w;
        f[4] = v1.x; f[5] = v1.y; f[6] = v1.z; f[7] = v1.w;
    }
    bf16x8 hi, mi;
#pragma unroll
    for (int e = 0; e < 8; e++) {
        __bf16 h = (__bf16)f[e];
        hi[e] = h; mi[e] = (__bf16)(f[e] - (float)h);
    }
    const int G = r * 4 + (slot ^ ((r >> 1) & 3));
    __bf16* blob = xp + (size_t)gk * 8192;
    *(bf16x8*)(blob + G * 8)        = hi;
    *(bf16x8*)(blob + 4096 + G * 8) = mi;
}

// ---- GEMM1: deep-pipelined (4 LDS buffers, counted vmcnt, 1 barrier/step).
// Per 32-k step-buffer (32 KB): [0,8K) x_h, [8K,16K) x_m, [16K,32K) W fp32.
// All staging via global_load_lds. 3-product bf16 hi/mid MFMA.
// grid: (4 h-tiles of 128, NS k-splits), block 512 = 8 waves (2t x 4h, 64x32).
__global__ __launch_bounds__(512) void k_gemm1(
    const float* __restrict__ aW1,   // [256][65536]
    const float* __restrict__ cW1,   // [256][65536]
    const __bf16* __restrict__ xp,   // packed x blobs
    float* __restrict__ P,           // [NS][100][512]
    int nsteps)                      // 32-k steps per split
{
    const int ht   = blockIdx.x;     // 0..3
    const int s    = blockIdx.y;
    const int tid  = threadIdx.x;
    const int lane = tid & 63;
    const int l31  = lane & 31;
    const int wv   = tid >> 6;           // 0..7
    const int wt   = (wv & 1) * 64;
    const int hq   = (wv >> 1) * 32;

    __shared__ __align__(16) char smem[4][32768];   // 128 KB

    const float* Wbase = (ht < 2) ? (aW1 + (size_t)ht * 128 * D_IN)
                                  : (cW1 + (size_t)(ht - 2) * 128 * D_IN);

    // staging invariants: 4 global_load_lds per thread per step
    const int gx0 = wv * 64 + lane;      // x granule op0 (0..511)
    const int gx1 = 512 + gx0;           // x granule op1 (512..1023)
    const int wr0 = gx0 >> 3, wj0 = gx0 & 7;   // W granule op2
    const int wr1 = gx1 >> 3, wj1 = gx1 & 7;   // W granule op3
    const float* wsrc0 = Wbase + (size_t)wr0 * D_IN + (wj0 ^ (wr0 & 7)) * 4;
    const float* wsrc1 = Wbase + (size_t)wr1 * D_IN + (wj1 ^ (wr1 & 7)) * 4;
    const int gk0 = s * nsteps;

    f32x16 acc0, acc1;
#pragma unroll
    for (int i = 0; i < 16; i++) { acc0[i] = 0.f; acc1[i] = 0.f; }

#define STAGE(i) do {                                                         \
    char* b_ = smem[(i) & 3];                                                 \
    const __bf16* xb_ = xp + (size_t)(gk0 + (i)) * 8192;                      \
    const int kc_ = (gk0 + (i)) * 32;                                         \
    gload_lds16(xb_ + gx0 * 8, b_ + gx0 * 16);                                \
    gload_lds16(xb_ + gx1 * 8, b_ + gx1 * 16);                                \
    gload_lds16(wsrc0 + kc_, b_ + 16384 + gx0 * 16);                          \
    gload_lds16(wsrc1 + kc_, b_ + 16384 + gx1 * 16);                          \
} while (0)

#define COMPUTE(i) do {                                                       \
    const char* b_ = smem[(i) & 3];                                           \
    _Pragma("unroll")                                                         \
    for (int s16 = 0; s16 < 2; s16++) {                                       \
        const int hr = hq + l31;                                              \
        const int gb = s16 * 4 + (lane >> 5) * 2;                             \
        const char* wrow_ = b_ + 16384 + hr * 128;                            \
        float4 wa = *(const float4*)(wrow_ + ((gb ^ (hr & 7)) * 16));         \
        float4 wb = *(const float4*)(wrow_ + (((gb + 1) ^ (hr & 7)) * 16));   \
        float fb[8] = {wa.x, wa.y, wa.z, wa.w, wb.x, wb.y, wb.z, wb.w};       \
        bf16x8 bh, bm;                                                        \
        _Pragma("unroll")                                                     \
        for (int e = 0; e < 8; e++) {                                         \
            __bf16 h = (__bf16)fb[e];                                         \
            bh[e] = h; bm[e] = (__bf16)(fb[e] - (float)h);                    \
        }                                                                     \
        const int slot = s16 * 2 + (lane >> 5);                               \
        const int r0 = wt + l31, r1 = r0 + 32;                                \
        const int G0 = r0 * 4 + (slot ^ ((r0 >> 1) & 3));                     \
        const int G1 = r1 * 4 + (slot ^ ((r1 >> 1) & 3));                     \
        bf16x8 a0h = *(const bf16x8*)(b_ + G0 * 16);                          \
        bf16x8 a0m = *(const bf16x8*)(b_ + 8192 + G0 * 16);                   \
        bf16x8 a1h = *(const bf16x8*)(b_ + G1 * 16);                          \
        bf16x8 a1m = *(const bf16x8*)(b_ + 8192 + G1 * 16);                   \
        acc0 = __builtin_amdgcn_mfma_f32_32x32x16_bf16(a0m, bh, acc0, 0,0,0); \
        acc0 = __builtin_amdgcn_mfma_f32_32x32x16_bf16(a0h, bm, acc0, 0,0,0); \
        acc0 = __builtin_amdgcn_mfma_f32_32x32x16_bf16(a0h, bh, acc0, 0,0,0); \
        acc1 = __builtin_amdgcn_mfma_f32_32x32x16_bf16(a1m, bh, acc1, 0,0,0); \
        acc1 = __builtin_amdgcn_mfma_f32_32x32x16_bf16(a1h, bm, acc1, 0,0,0); \
        acc1 = __builtin_amdgcn_mfma_f32_32x32x16_bf16(a1h, bh, acc1, 0,0,0); \
    }                                                                         \
} while (0)

    STAGE(0);
    if (nsteps > 1) STAGE(1);
    if (nsteps > 2) STAGE(2);
    for (int i = 0; i < nsteps; i++) {
        const int rem = nsteps - 1 - i;
        if (rem >= 2)      asm volatile("s_waitcnt vmcnt(8)" ::: "memory");
        else if (rem == 1) asm volatile("s_waitcnt vmcnt(4)" ::: "memory");
        else               asm volatile("s_waitcnt vmcnt(0)" ::: "memory");
        __builtin_amdgcn_s_barrier();
        __builtin_amdgcn_sched_barrier(0);
        if (i + 3 < nsteps) STAGE(i + 3);
        COMPUTE(i);
    }
#undef STAGE
#undef COMPUTE

    // ---- store partials
    const int rbase = 4 * (lane >> 5);
    const int hcol  = ht * 128 + hq + l31;
    float* Pb = P + (size_t)s * T_STEPS * HTOT;
#pragma unroll
    for (int reg = 0; reg < 16; reg++) {
        const int row = (reg & 3) + rbase + 8 * (reg >> 2);
        const int t0  = wt + row;
        const int t1  = wt + 32 + row;
        if (t0 < T_STEPS) Pb[(size_t)t0 * HTOT + hcol] = acc0[reg];
        if (t1 < T_STEPS) Pb[(size_t)t1 * HTOT + hcol] = acc1[reg];
    }
}

// reduce partials + bias -> cur1[t][h]   (float4 per thread)
__global__ __launch_bounds__(256) void k_reduce(
    const float* __restrict__ P,
    const float* __restrict__ ab1, const float* __restrict__ cb1,
    float* __restrict__ cur1, int NS)
{
    int g4 = blockIdx.x * 256 + threadIdx.x;
    int g  = g4 * 4;
    int h0 = g & (HTOT - 1);
    float4 sum;
    sum.x = (h0 + 0 < HID) ? ab1[h0 + 0] : cb1[h0 + 0 - HID];
    sum.y = (h0 + 1 < HID) ? ab1[h0 + 1] : cb1[h0 + 1 - HID];
    sum.z = (h0 + 2 < HID) ? ab1[h0 + 2] : cb1[h0 + 2 - HID];
    sum.w = (h0 + 3 < HID) ? ab1[h0 + 3] : cb1[h0 + 3 - HID];
    for (int ss = 0; ss < NS; ss++) {
        float4 v = *(const float4*)(P + (size_t)ss * T_STEPS * HTOT + g);
        sum.x += v.x; sum.y += v.y; sum.z += v.z; sum.w += v.w;
    }
    *(float4*)(cur1 + g) = sum;
}

// LIF1: 8 blocks x 64 threads, thread = neuron, 10-deep current prefetch.
__global__ __launch_bounds__(64) void k_lif1(
    const float* __restrict__ cur1,
    unsigned long long* __restrict__ bitsws,
    float* __restrict__ wsa)
{
    const int b    = blockIdx.x;
    const int lane = threadIdx.x;
    const int n    = b * 64 + lane;

    float mem = 0.f;
    for (int tb = 0; tb < T_STEPS; tb += 10) {
        float c[10];
#pragma unroll
        for (int i = 0; i < 10; i++) c[i] = cur1[(size_t)(tb + i) * HTOT + n];
#pragma unroll
        for (int i = 0; i < 10; i++) {
            float reset = (mem > THRESH) ? THRESH : 0.f;
            mem = BETA * mem + c[i] - reset;
            unsigned long long m = __ballot(mem > THRESH);
            if (lane == 0) bitsws[(size_t)(tb + i) * 8 + b] = m;
        }
    }
    if (b == 0 && lane == 0) { wsa[0] = 0.f; wsa[1] = 0.f; }
}

// GEMM2 + LIF2: block per output neuron j (0..19 actor, 20 critic).
__global__ __launch_bounds__(128) void k_gemm2(
    const unsigned long long* __restrict__ bitsws,
    const float* __restrict__ aW2, const float* __restrict__ ab2,
    const float* __restrict__ cW2, const float* __restrict__ cb2,
    float* __restrict__ wsa, float* __restrict__ out)
{
    const int j   = blockIdx.x;
    const int tid = threadIdx.x;

    __shared__ float W[256];
    __shared__ float c2[T_STEPS];

    const float* Wsrc = (j < 20) ? (aW2 + j * 256) : cW2;
    for (int i = tid; i < 256; i += 128) W[i] = Wsrc[i];
    const float bias  = (j < 20) ? ab2[j] : cb2[0];
    const int   wbase = (j < 20) ? 0 : 4;
    __syncthreads();

    const int t = tid;
    if (t < T_STEPS) {
        unsigned long long m0 = bitsws[(size_t)t * 8 + wbase + 0];
        unsigned long long m1 = bitsws[(size_t)t * 8 + wbase + 1];
        unsigned long long m2 = bitsws[(size_t)t * 8 + wbase + 2];
        unsigned long long m3 = bitsws[(size_t)t * 8 + wbase + 3];
        float acc = bias;
#pragma unroll
        for (int bitp = 0; bitp < 64; bitp++) {
            acc += ((m0 >> bitp) & 1ULL) ? W[bitp]       : 0.f;
            acc += ((m1 >> bitp) & 1ULL) ? W[64 + bitp]  : 0.f;
            acc += ((m2 >> bitp) & 1ULL) ? W[128 + bitp] : 0.f;
            acc += ((m3 >> bitp) & 1ULL) ? W[192 + bitp] : 0.f;
        }
        c2[t] = acc;
    }
    __syncthreads();

    if (tid == 0) {
        float mem = 0.f, spk = 0.f;
        for (int tt = 0; tt < T_STEPS; tt++) {
            float reset = (mem > THRESH) ? THRESH : 0.f;
            mem = BETA * mem + c2[tt] - reset;
            spk += (mem > THRESH) ? 1.f : 0.f;
        }
        if (j < 10)       atomicAdd(&wsa[0], spk);   // exact: integer-valued floats
        else if (j < 20)  atomicAdd(&wsa[1], spk);
        else              out[2] = mem;
    }
}

__global__ __launch_bounds__(64) void k_final(
    const float* __restrict__ wsa, float* __restrict__ out)
{
    if (threadIdx.x == 0) {
        float a0 = wsa[0], a1 = wsa[1];
        float mx = fmaxf(a0, a1);
        float e0 = expf(a0 - mx), e1 = expf(a1 - mx);
        float inv = 1.f / (e0 + e1);
        out[0] = e0 * inv;
        out[1] = e1 * inv;
    }
}

extern "C" void kernel_launch(void* const* d_in, const int* in_sizes, int n_in,
                              void* d_out, int out_size, void* d_ws, size_t ws_size,
                              hipStream_t stream) {
    const float* x   = (const float*)d_in[0];
    const float* aW1 = (const float*)d_in[1];
    const float* ab1 = (const float*)d_in[2];
    const float* aW2 = (const float*)d_in[3];
    const float* ab2 = (const float*)d_in[4];
    const float* cW1 = (const float*)d_in[5];
    const float* cb1 = (const float*)d_in[6];
    const float* cW2 = (const float*)d_in[7];
    const float* cb2 = (const float*)d_in[8];
    float* out = (float*)d_out;

    const size_t xpack_bytes = 2048ull * 16384;            // 33.55 MB
    int NS = 64;
    while (NS > 8 &&
           xpack_bytes + ((size_t)(NS + 1) * T_STEPS * HTOT) * sizeof(float)
               + 8192 > ws_size)
        NS >>= 1;
    const int nsteps = (D_IN / NS) / 32;

    __bf16* xpack = (__bf16*)d_ws;
    float*  P     = (float*)((char*)d_ws + xpack_bytes);   // [NS][100][512]
    float*  cur1  = P + (size_t)NS * T_STEPS * HTOT;
    unsigned long long* bitsws =
        (unsigned long long*)(cur1 + T_STEPS * HTOT);      // [100][8]
    float* wsa = (float*)(bitsws + T_STEPS * 8);           // [2]

    k_xpack <<<2048, 512, 0, stream>>>(x, xpack);
    k_gemm1 <<<dim3(4, NS), 512, 0, stream>>>(aW1, cW1, xpack, P, nsteps);
    k_reduce<<<(T_STEPS * HTOT / 4) / 256, 256, 0, stream>>>(P, ab1, cb1, cur1, NS);
    k_lif1  <<<8, 64, 0, stream>>>(cur1, bitsws, wsa);
    k_gemm2 <<<21, 128, 0, stream>>>(bitsws, aW2, ab2, cW2, cb2, wsa, out);
    k_final <<<1, 64, 0, stream>>>(wsa, out);
}